// Round 15
// baseline (55.323 us; speedup 1.0000x reference)
//
#include <hip/hip_runtime.h>
#include <hip/hip_fp16.h>
#include <math.h>

#define B_ 2
#define C_ 256
#define H_ 64
#define W_ 64
#define L_ 4096
#define HEADS_ 8
#define DH_ 32
#define CG_ 8
#define K_ 7
#define PAD_ 3
#define K2_ 49
#define PW_ 70
#define PPIX_ 4900
#define PADT_ ((size_t)B_*HEADS_*CG_*PPIX_)    // 627200 uint2 (f16x4) per padded tensor
#define WS_STR 72                               // LDS row stride in f16 elems (144B)

typedef _Float16 f16x8 __attribute__((ext_vector_type(8)));
typedef _Float16 h2    __attribute__((ext_vector_type(2)));
typedef float    f32x4 __attribute__((ext_vector_type(4)));

__device__ inline h2 u2h(unsigned u) { union { unsigned u; h2 h; } c; c.u = u; return c.h; }
__device__ inline h2 cvt2h(float a, float b) {
    auto r = __builtin_amdgcn_cvt_pkrtz(a, b);      // __fp16 ext_vector(2)
    union { decltype(r) s; h2 d; } c; c.s = r; return c.d;
}
__device__ inline unsigned pkh(float a, float b) {
    union { h2 h; unsigned u; } c; c.h = cvt2h(a, b); return c.u;
}

// ---------------- Kernel A: QKV projection via f16 MFMA + halo-zero slice ---
// z = 0..5: GEMM (which = z>>1, b = z&1), 128 o x 64 l per block.
//           Weights read f32 COALESCED (16 lanes x float4 = 256B per o-row)
//           and converted inline during LDS staging (no prepack kernel).
// z = 6:    K/V halo zeroing, direct halo-cell enumeration (804 cells/plane).
__global__ __launch_bounds__(256) void qkv_mfma(
    const float* __restrict__ q_in, const float* __restrict__ k_in, const float* __restrict__ v_in,
    const float* __restrict__ wq, const float* __restrict__ wk, const float* __restrict__ wv,
    const float* __restrict__ bq, const float* __restrict__ bk, const float* __restrict__ bv,
    uint2* __restrict__ qt2, uint2* __restrict__ kt2, uint2* __restrict__ vt2)
{
    const int z = blockIdx.z;
    const int tid = threadIdx.x;

    if (z == 6) {
        // zero only halo cells: top3/bottom3 rows (420) + 64 mid rows x 6 (384)
        const int flat = blockIdx.x + 64*blockIdx.y;   // 0..127
        const uint2 zz = make_uint2(0u, 0u);
        for (int e = flat*256 + tid; e < 128*804; e += 128*256) {
            int pl = e / 804;
            int c  = e - pl*804;
            int py, px;
            if (c < 210)      { py = c/70;            px = c%70; }
            else if (c < 420) { int c2 = c-210; py = 67 + c2/70; px = c2%70; }
            else              { int c2 = c-420; py = 3 + c2/6; int j = c2%6; px = (j<3) ? j : 64+j; }
            size_t idx = (size_t)pl*PPIX_ + (size_t)py*PW_ + px;
            kt2[idx] = zz;
            vt2[idx] = zz;
        }
        return;
    }

    const int which = z >> 1;      // 0=q,1=k,2=v
    const int b = z & 1;
    const float* X    = (which==0) ? q_in : (which==1 ? k_in : v_in);
    const float* wsrc = (which==0) ? wq   : (which==1 ? wk   : wv);
    const float* bias = (which==0) ? bq   : (which==1 ? bk   : bv);

    const int y    = blockIdx.x;
    const int l0   = y * 64;
    const int o_t0 = blockIdx.y * 128;
    const int lane = tid & 63, wave = tid >> 6;
    const int orow = lane & 15, kgrp = lane >> 4;

    __shared__ _Float16 Ws[128*WS_STR];   // weights [o][c-chunk]  (18.4 KB)
    __shared__ _Float16 Xs[64*WS_STR];    // input^T [l][c-chunk]  (9.2 KB)

    f32x4 acc[2][4] = {};

    for (int ch = 0; ch < 4; ++ch) {
        const int c0 = ch*64;
        // Ws staging: f32 coalesced (lane c4 -> 16B of o-row), cvt inline
        #pragma unroll
        for (int i = 0; i < 8; ++i) {
            int o  = i*16 + (tid>>4);
            int c4 = tid & 15;
            float4 wv4 = *reinterpret_cast<const float4*>(&wsrc[(size_t)(o_t0 + o)*C_ + c0 + c4*4]);
            uint2 pk = make_uint2(pkh(wv4.x, wv4.y), pkh(wv4.z, wv4.w));
            *reinterpret_cast<uint2*>(&Ws[o*WS_STR + c4*4]) = pk;
        }
        // Xs staging: float4 along l (4 VMEM instrs/chunk), f16 transpose writes
        #pragma unroll
        for (int i = 0; i < 4; ++i) {
            int c_loc = (tid>>4) + i*16;        // 0..63
            int l4    = (tid&15)*4;             // 0,4,...,60
            float4 xv = *reinterpret_cast<const float4*>(&X[(size_t)(b*C_ + c0 + c_loc)*L_ + l0 + l4]);
            Xs[(l4+0)*WS_STR + c_loc] = (_Float16)xv.x;
            Xs[(l4+1)*WS_STR + c_loc] = (_Float16)xv.y;
            Xs[(l4+2)*WS_STR + c_loc] = (_Float16)xv.z;
            Xs[(l4+3)*WS_STR + c_loc] = (_Float16)xv.w;
        }
        __syncthreads();
        #pragma unroll
        for (int kk = 0; kk < 2; ++kk) {
            f16x8 af[2], bfr[4];
            #pragma unroll
            for (int fo = 0; fo < 2; ++fo)
                af[fo] = *reinterpret_cast<const f16x8*>(&Ws[(wave*32 + fo*16 + orow)*WS_STR + kk*32 + kgrp*8]);
            #pragma unroll
            for (int fn = 0; fn < 4; ++fn)
                bfr[fn] = *reinterpret_cast<const f16x8*>(&Xs[(fn*16 + orow)*WS_STR + kk*32 + kgrp*8]);
            #pragma unroll
            for (int fo = 0; fo < 2; ++fo)
                #pragma unroll
                for (int fn = 0; fn < 4; ++fn)
                    acc[fo][fn] = __builtin_amdgcn_mfma_f32_16x16x32_f16(af[fo], bfr[fn], acc[fo][fn], 0, 0, 0);
        }
        __syncthreads();
    }

    #pragma unroll
    for (int fo = 0; fo < 2; ++fo) {
        const int og = o_t0 + wave*32 + fo*16 + kgrp*4;
        const float4 b4 = *reinterpret_cast<const float4*>(&bias[og]);
        const size_t p = (size_t)(b*64 + (og >> 2));   // plane index
        #pragma unroll
        for (int fn = 0; fn < 4; ++fn) {
            const int xl = fn*16 + orow;
            uint2 r = make_uint2(pkh(acc[fo][fn][0] + b4.x, acc[fo][fn][1] + b4.y),
                                 pkh(acc[fo][fn][2] + b4.z, acc[fo][fn][3] + b4.w));
            if (which == 0) {
                qt2[p*L_ + l0 + xl] = r;
            } else {
                uint2* dst = (which==1) ? kt2 : vt2;
                dst[p*PPIX_ + (size_t)(y+PAD_)*PW_ + (xl+PAD_)] = r;
            }
        }
    }
}

// ---------------- Kernel B: 7x7 local attention, f16, dot2/pk_fma -----------
// Block = (plane=b*8+h, image row y), 256 threads (4 waves), grid 1024.
__global__ __launch_bounds__(256) void local_attn(
    uint2* __restrict__ qt2, const uint2* __restrict__ kt2, const uint2* __restrict__ vt2)
{
    const int tid = threadIdx.x;
    const int w = tid >> 6, x = tid & 63;
    const int bid = blockIdx.x;
    const int plane = bid & 15;      // plane -> XCD plane%8: K/V L2-resident per XCD
    const int y = bid >> 4;          // 0..63

    const uint2* kb = kt2 + (size_t)plane*CG_*PPIX_;
    const uint2* vb = vt2 + (size_t)plane*CG_*PPIX_;
    uint2* qpl = qt2 + (size_t)plane*CG_*L_;

    __shared__ float S[K2_][64];     // holds P = exp(logit*scale); 12.25 KB

    const float scale = 0.0625f; // 1/sqrt(256)

    // ---- QK: my window rows r = w and w+4 (v_dot2_f32_f16) ----
    float lg[2][K_] = {};
    #pragma unroll
    for (int cg=0; cg<CG_; ++cg) {
        uint2 qu = qpl[(size_t)cg*L_ + y*W_ + x];
        const h2 q01 = u2h(qu.x), q23 = u2h(qu.y);
        #pragma unroll
        for (int rr=0; rr<2; ++rr) {
            const int r = w + rr*4;
            if (r > 6) continue;                  // only w=3,rr=1 skips (uniform)
            const uint2* row = kb + (size_t)cg*PPIX_ + (size_t)(y + r)*PW_ + x;
            #pragma unroll
            for (int kx=0; kx<K_; ++kx) {
                uint2 kk = row[kx];
                lg[rr][kx] = __builtin_amdgcn_fdot2(q01, u2h(kk.x), lg[rr][kx], false);
                lg[rr][kx] = __builtin_amdgcn_fdot2(q23, u2h(kk.y), lg[rr][kx], false);
            }
        }
    }
    #pragma unroll
    for (int rr=0; rr<2; ++rr) {
        const int r = w + rr*4;
        if (r <= 6) {
            #pragma unroll
            for (int kx=0; kx<K_; ++kx) S[r*K_+kx][x] = __expf(lg[rr][kx]*scale);
        }
    }
    __syncthreads();

    // ---- denominator: plain sum of P from LDS ----
    float sum = 0.f;
    #pragma unroll
    for (int i=0;i<K2_;++i) sum += S[i][x];
    const float inv = 1.0f/sum;

    // ---- PV: my channel-groups {2w, 2w+1}; packed f16 fma, f32 row carry ----
    const int cg0 = w*2, cg1 = w*2 + 1;
    float4 a0 = make_float4(0.f,0.f,0.f,0.f);
    float4 a1 = make_float4(0.f,0.f,0.f,0.f);
    #pragma unroll
    for (int r=0; r<K_; ++r) {
        const uint2* row0 = vb + (size_t)cg0*PPIX_ + (size_t)(y + r)*PW_ + x;
        const uint2* row1 = vb + (size_t)cg1*PPIX_ + (size_t)(y + r)*PW_ + x;
        h2 ra0 = (h2)0, ra1 = (h2)0, rb0 = (h2)0, rb1 = (h2)0;
        #pragma unroll
        for (int kx=0; kx<K_; ++kx) {
            const float p = S[r*K_+kx][x];
            const h2 p2 = cvt2h(p, p);
            uint2 u0 = row0[kx];
            uint2 u1 = row1[kx];
            ra0 += p2 * u2h(u0.x);
            ra1 += p2 * u2h(u0.y);
            rb0 += p2 * u2h(u1.x);
            rb1 += p2 * u2h(u1.y);
        }
        a0.x += (float)ra0[0]; a0.y += (float)ra0[1];
        a0.z += (float)ra1[0]; a0.w += (float)ra1[1];
        a1.x += (float)rb0[0]; a1.y += (float)rb0[1];
        a1.z += (float)rb1[0]; a1.w += (float)rb1[1];
    }
    qpl[(size_t)cg0*L_ + y*W_ + x] = make_uint2(pkh(a0.x*inv, a0.y*inv), pkh(a0.z*inv, a0.w*inv));
    qpl[(size_t)cg1*L_ + y*W_ + x] = make_uint2(pkh(a1.x*inv, a1.y*inv), pkh(a1.z*inv, a1.w*inv));
}

// ---------------- Kernel C: output projection via f16 MFMA (64-o tiles) -----
// grid (64, 4, 2) = 512 blocks. Weights f32 coalesced + inline cvt; X uint2 copy.
__global__ __launch_bounds__(256) void out_mfma(
    const uint2* __restrict__ qt2, const float* __restrict__ wo,
    const float* __restrict__ bo, float* __restrict__ out)
{
    const int b    = blockIdx.z;
    const int l0   = blockIdx.x * 64;
    const int o_t0 = blockIdx.y * 64;
    const int tid  = threadIdx.x;
    const int lane = tid & 63, wave = tid >> 6;
    const int orow = lane & 15, kgrp = lane >> 4;

    __shared__ _Float16 Ws[64*WS_STR];    // 9.2 KB
    __shared__ _Float16 Xs[64*WS_STR];    // 9.2 KB

    f32x4 acc[4] = {};
    const int cq  = tid >> 6;
    const int lst = tid & 63;

    for (int ch = 0; ch < 4; ++ch) {
        const int c0 = ch*64;
        #pragma unroll
        for (int i = 0; i < 4; ++i) {
            int o  = i*16 + (tid>>4);
            int c4 = tid & 15;
            float4 wv4 = *reinterpret_cast<const float4*>(&wo[(size_t)(o_t0 + o)*C_ + c0 + c4*4]);
            uint2 pk = make_uint2(pkh(wv4.x, wv4.y), pkh(wv4.z, wv4.w));
            *reinterpret_cast<uint2*>(&Ws[o*WS_STR + c4*4]) = pk;
        }
        #pragma unroll
        for (int i = 0; i < 4; ++i) {
            int c4i = i*4 + cq;
            uint2 v = qt2[(size_t)(b*64 + (c0>>2) + c4i)*L_ + l0 + lst];
            *reinterpret_cast<uint2*>(&Xs[lst*WS_STR + c4i*4]) = v;
        }
        __syncthreads();
        #pragma unroll
        for (int kk = 0; kk < 2; ++kk) {
            f16x8 af, bfr[4];
            af = *reinterpret_cast<const f16x8*>(&Ws[(wave*16 + orow)*WS_STR + kk*32 + kgrp*8]);
            #pragma unroll
            for (int fn = 0; fn < 4; ++fn)
                bfr[fn] = *reinterpret_cast<const f16x8*>(&Xs[(fn*16 + orow)*WS_STR + kk*32 + kgrp*8]);
            #pragma unroll
            for (int fn = 0; fn < 4; ++fn)
                acc[fn] = __builtin_amdgcn_mfma_f32_16x16x32_f16(af, bfr[fn], acc[fn], 0, 0, 0);
        }
        __syncthreads();
    }

    {
        const int o_base = o_t0 + wave*16 + kgrp*4;
        #pragma unroll
        for (int fn = 0; fn < 4; ++fn) {
            const int xl = fn*16 + orow;
            #pragma unroll
            for (int r = 0; r < 4; ++r)
                out[(size_t)(b*C_ + o_base + r)*L_ + l0 + xl] = acc[fn][r] + bo[o_base + r];
        }
    }
}

extern "C" void kernel_launch(void* const* d_in, const int* in_sizes, int n_in,
                              void* d_out, int out_size, void* d_ws, size_t ws_size,
                              hipStream_t stream) {
    const float* queries = (const float*)d_in[0];
    const float* keys    = (const float*)d_in[1];
    const float* values  = (const float*)d_in[2];
    const float* wq = (const float*)d_in[3];
    const float* bq = (const float*)d_in[4];
    const float* wk = (const float*)d_in[5];
    const float* bk = (const float*)d_in[6];
    const float* wv = (const float*)d_in[7];
    const float* bv = (const float*)d_in[8];
    const float* wo = (const float*)d_in[9];
    const float* bo = (const float*)d_in[10];
    float* out = (float*)d_out;

    uint2* qt2 = (uint2*)d_ws;                             // Q f16 planar, attn out in-place
    uint2* kt2 = qt2 + (size_t)B_*HEADS_*CG_*L_;           // padded planar K (f16 x4)
    uint2* vt2 = kt2 + PADT_;                              // padded planar V (f16 x4)

    qkv_mfma<<<dim3(64, 2, 7), 256, 0, stream>>>(queries, keys, values,
                                                 wq, wk, wv, bq, bk, bv, qt2, kt2, vt2);
    local_attn<<<1024, 256, 0, stream>>>(qt2, kt2, vt2);
    out_mfma<<<dim3(64, 4, 2), 256, 0, stream>>>(qt2, wo, bo, out);
}

// Round 16
// 52.799 us; speedup vs baseline: 1.0478x; 1.0478x over previous
//
#include <hip/hip_runtime.h>
#include <hip/hip_fp16.h>
#include <math.h>

#define B_ 2
#define C_ 256
#define H_ 64
#define W_ 64
#define L_ 4096
#define HEADS_ 8
#define DH_ 32
#define K_ 7
#define PAD_ 3
#define K2_ 49
#define PW_ 70
#define PPIX_ 4900
#define NPP_ 4                                  // pair-planes (8ch) per (b,h)
#define PADT4_ ((size_t)B_*HEADS_*NPP_*PPIX_)   // 313600 uint4 per padded tensor
#define WS_STR 72                               // LDS row stride in f16 elems (144B)

typedef _Float16 f16x8 __attribute__((ext_vector_type(8)));
typedef _Float16 h2    __attribute__((ext_vector_type(2)));
typedef float    f32x4 __attribute__((ext_vector_type(4)));

__device__ inline h2 u2h(unsigned u) { union { unsigned u; h2 h; } c; c.u = u; return c.h; }
__device__ inline h2 cvt2h(float a, float b) {
    auto r = __builtin_amdgcn_cvt_pkrtz(a, b);      // __fp16 ext_vector(2)
    union { decltype(r) s; h2 d; } c; c.s = r; return c.d;
}
__device__ inline unsigned pkh(float a, float b) {
    union { h2 h; unsigned u; } c; c.h = cvt2h(a, b); return c.u;
}

// ---------------- Kernel A: weight pack (f16) ------------------------------
__global__ __launch_bounds__(256) void prep(
    const float* __restrict__ wq, const float* __restrict__ wk,
    const float* __restrict__ wv, const float* __restrict__ wo,
    unsigned* __restrict__ wb)
{
    int idx = blockIdx.x*256 + threadIdx.x;   // 0..131071
    const float* src = (idx < 32768) ? wq : (idx < 65536) ? wk : (idx < 98304) ? wv : wo;
    int off = (idx & 32767) * 2;
    wb[idx] = pkh(src[off], src[off+1]);
}

// ---------------- Kernel B: QKV projection via f16 MFMA + halo-zero slice ---
// z = 0..5: GEMM (which = z>>1, b = z&1), 128 o x 64 l per block.
// z = 6:    K/V halo zeroing (uint4 pair-plane layout, direct enumeration).
// Outputs f16 in PAIR-PLANE layout: uint4 cell = 8 channels (o>>3), the two
// uint2 halves written by lanes holding og and og+4 of the same wave store.
__global__ __launch_bounds__(256) void qkv_mfma(
    const float* __restrict__ q_in, const float* __restrict__ k_in, const float* __restrict__ v_in,
    const unsigned* __restrict__ wb,
    const float* __restrict__ bq, const float* __restrict__ bk, const float* __restrict__ bv,
    uint2* __restrict__ qt_u2, uint2* __restrict__ kt_u2, uint2* __restrict__ vt_u2,
    uint4* __restrict__ kt_u4, uint4* __restrict__ vt_u4)
{
    const int z = blockIdx.z;
    const int tid = threadIdx.x;

    if (z == 6) {
        // zero halo cells of 64 pair-planes: top3/bottom3 rows (420) + 64x6 (384)
        const int flat = blockIdx.x + 64*blockIdx.y;   // 0..127
        const uint4 zz = make_uint4(0u,0u,0u,0u);
        for (int e = flat*256 + tid; e < 64*804; e += 128*256) {
            int pl = e / 804;
            int c  = e - pl*804;
            int py, px;
            if (c < 210)      { py = c/70;            px = c%70; }
            else if (c < 420) { int c2 = c-210; py = 67 + c2/70; px = c2%70; }
            else              { int c2 = c-420; py = 3 + c2/6; int j = c2%6; px = (j<3) ? j : 64+j; }
            size_t idx = (size_t)pl*PPIX_ + (size_t)py*PW_ + px;
            kt_u4[idx] = zz;
            vt_u4[idx] = zz;
        }
        return;
    }

    const int which = z >> 1;      // 0=q,1=k,2=v
    const int b = z & 1;
    const float* X = (which==0) ? q_in : (which==1 ? k_in : v_in);
    const unsigned* wbp = wb + which*32768;
    const float* bias = (which==0) ? bq : (which==1 ? bk : bv);

    const int y    = blockIdx.x;
    const int l0   = y * 64;
    const int o_t0 = blockIdx.y * 128;
    const int lane = tid & 63, wave = tid >> 6;
    const int orow = lane & 15, kgrp = lane >> 4;

    __shared__ _Float16 Ws[128*WS_STR];   // weights [o][c-chunk]  (18.4 KB)
    __shared__ _Float16 Xs[64*WS_STR];    // input^T [l][c-chunk]  (9.2 KB)

    f32x4 acc[2][4] = {};

    for (int ch = 0; ch < 4; ++ch) {
        const int c0 = ch*64;
        #pragma unroll
        for (int i = 0; i < 8; ++i) {
            int o  = i*16 + (tid>>4);
            int c4 = tid & 15;
            uint2 v = *reinterpret_cast<const uint2*>(wbp + (size_t)(o_t0 + o)*128 + (c0>>1) + c4*2);
            *reinterpret_cast<uint2*>(&Ws[o*WS_STR + c4*4]) = v;
        }
        // Xs staging: float4 along l (4 VMEM instrs/chunk), f16 transpose writes
        #pragma unroll
        for (int i = 0; i < 4; ++i) {
            int c_loc = (tid>>4) + i*16;        // 0..63
            int l4    = (tid&15)*4;             // 0,4,...,60
            float4 xv = *reinterpret_cast<const float4*>(&X[(size_t)(b*C_ + c0 + c_loc)*L_ + l0 + l4]);
            Xs[(l4+0)*WS_STR + c_loc] = (_Float16)xv.x;
            Xs[(l4+1)*WS_STR + c_loc] = (_Float16)xv.y;
            Xs[(l4+2)*WS_STR + c_loc] = (_Float16)xv.z;
            Xs[(l4+3)*WS_STR + c_loc] = (_Float16)xv.w;
        }
        __syncthreads();
        #pragma unroll
        for (int kk = 0; kk < 2; ++kk) {
            f16x8 af[2], bfr[4];
            #pragma unroll
            for (int fo = 0; fo < 2; ++fo)
                af[fo] = *reinterpret_cast<const f16x8*>(&Ws[(wave*32 + fo*16 + orow)*WS_STR + kk*32 + kgrp*8]);
            #pragma unroll
            for (int fn = 0; fn < 4; ++fn)
                bfr[fn] = *reinterpret_cast<const f16x8*>(&Xs[(fn*16 + orow)*WS_STR + kk*32 + kgrp*8]);
            #pragma unroll
            for (int fo = 0; fo < 2; ++fo)
                #pragma unroll
                for (int fn = 0; fn < 4; ++fn)
                    acc[fo][fn] = __builtin_amdgcn_mfma_f32_16x16x32_f16(af[fo], bfr[fn], acc[fo][fn], 0, 0, 0);
        }
        __syncthreads();
    }

    #pragma unroll
    for (int fo = 0; fo < 2; ++fo) {
        const int og = o_t0 + wave*32 + fo*16 + kgrp*4;
        const float4 b4 = *reinterpret_cast<const float4*>(&bias[og]);
        const size_t pp = (size_t)(b*32 + (og >> 3));   // pair-plane index
        const int half = (og >> 2) & 1;
        #pragma unroll
        for (int fn = 0; fn < 4; ++fn) {
            const int xl = fn*16 + orow;
            uint2 r = make_uint2(pkh(acc[fo][fn][0] + b4.x, acc[fo][fn][1] + b4.y),
                                 pkh(acc[fo][fn][2] + b4.z, acc[fo][fn][3] + b4.w));
            if (which == 0) {
                qt_u2[(pp*L_ + l0 + xl)*2 + half] = r;
            } else {
                uint2* dst = (which==1) ? kt_u2 : vt_u2;
                dst[(pp*PPIX_ + (size_t)(y+PAD_)*PW_ + (xl+PAD_))*2 + half] = r;
            }
        }
    }
}

// ---------------- Kernel C: 7x7 local attention, uint4 pair-plane f16 -------
// Block = (plane=b*8+h, image row y), 256 threads (4 waves), grid 1024.
// QK: wave w -> window rows {w, w+4}; 56 uint4 loads (was 112 uint2).
// PV: wave w -> pair-plane w (8 channels); 49 uint4 loads (was 98 uint2).
__global__ __launch_bounds__(256) void local_attn(
    uint4* __restrict__ qt, const uint4* __restrict__ kt, const uint4* __restrict__ vt)
{
    const int tid = threadIdx.x;
    const int w = tid >> 6, x = tid & 63;
    const int bid = blockIdx.x;
    const int plane = bid & 15;      // plane -> XCD plane%8: K/V L2-resident per XCD
    const int y = bid >> 4;          // 0..63

    const uint4* kb = kt + (size_t)plane*NPP_*PPIX_;
    const uint4* vb = vt + (size_t)plane*NPP_*PPIX_;
    uint4* qpl = qt + (size_t)plane*NPP_*L_;

    __shared__ float S[K2_][64];     // holds P = exp(logit*scale); 12.25 KB

    const float scale = 0.0625f; // 1/sqrt(256)

    // ---- QK: my window rows r = w and w+4 (v_dot2_f32_f16) ----
    float lg[2][K_] = {};
    #pragma unroll
    for (int pp=0; pp<NPP_; ++pp) {
        uint4 qu = qpl[(size_t)pp*L_ + y*W_ + x];
        const h2 q0 = u2h(qu.x), q1 = u2h(qu.y), q2 = u2h(qu.z), q3 = u2h(qu.w);
        #pragma unroll
        for (int rr=0; rr<2; ++rr) {
            const int r = w + rr*4;
            if (r > 6) continue;                  // only w=3,rr=1 skips (uniform)
            const uint4* row = kb + (size_t)pp*PPIX_ + (size_t)(y + r)*PW_ + x;
            #pragma unroll
            for (int kx=0; kx<K_; ++kx) {
                uint4 kk = row[kx];
                float d = lg[rr][kx];
                d = __builtin_amdgcn_fdot2(q0, u2h(kk.x), d, false);
                d = __builtin_amdgcn_fdot2(q1, u2h(kk.y), d, false);
                d = __builtin_amdgcn_fdot2(q2, u2h(kk.z), d, false);
                d = __builtin_amdgcn_fdot2(q3, u2h(kk.w), d, false);
                lg[rr][kx] = d;
            }
        }
    }
    #pragma unroll
    for (int rr=0; rr<2; ++rr) {
        const int r = w + rr*4;
        if (r <= 6) {
            #pragma unroll
            for (int kx=0; kx<K_; ++kx) S[r*K_+kx][x] = __expf(lg[rr][kx]*scale);
        }
    }
    __syncthreads();

    // ---- denominator: plain sum of P from LDS ----
    float sum = 0.f;
    #pragma unroll
    for (int i=0;i<K2_;++i) sum += S[i][x];
    const float inv = 1.0f/sum;

    // ---- PV: my pair-plane (= w, 8 channels); packed f16 fma, f32 row carry --
    const uint4* plv = vb + (size_t)w*PPIX_;
    float4 a0 = make_float4(0.f,0.f,0.f,0.f);
    float4 a1 = make_float4(0.f,0.f,0.f,0.f);
    #pragma unroll
    for (int r=0; r<K_; ++r) {
        const uint4* row = plv + (size_t)(y + r)*PW_ + x;
        h2 ra0 = (h2)0, ra1 = (h2)0, rb0 = (h2)0, rb1 = (h2)0;
        #pragma unroll
        for (int kx=0; kx<K_; ++kx) {
            const float p = S[r*K_+kx][x];
            const h2 p2 = cvt2h(p, p);
            uint4 u = row[kx];
            ra0 += p2 * u2h(u.x);
            ra1 += p2 * u2h(u.y);
            rb0 += p2 * u2h(u.z);
            rb1 += p2 * u2h(u.w);
        }
        a0.x += (float)ra0[0]; a0.y += (float)ra0[1];
        a0.z += (float)ra1[0]; a0.w += (float)ra1[1];
        a1.x += (float)rb0[0]; a1.y += (float)rb0[1];
        a1.z += (float)rb1[0]; a1.w += (float)rb1[1];
    }
    qpl[(size_t)w*L_ + y*W_ + x] = make_uint4(pkh(a0.x*inv, a0.y*inv), pkh(a0.z*inv, a0.w*inv),
                                              pkh(a1.x*inv, a1.y*inv), pkh(a1.z*inv, a1.w*inv));
}

// ---------------- Kernel D: output projection via f16 MFMA (64-o tiles) -----
// grid (64, 4, 2) = 512 blocks. X staging: 2 uint4 loads/chunk (pair-plane).
__global__ __launch_bounds__(256) void out_mfma(
    const uint4* __restrict__ qt, const unsigned* __restrict__ wb,
    const float* __restrict__ bo, float* __restrict__ out)
{
    const int b    = blockIdx.z;
    const int l0   = blockIdx.x * 64;
    const int o_t0 = blockIdx.y * 64;
    const unsigned* wbp = wb + 3*32768;
    const int tid  = threadIdx.x;
    const int lane = tid & 63, wave = tid >> 6;
    const int orow = lane & 15, kgrp = lane >> 4;

    __shared__ _Float16 Ws[64*WS_STR];    // 9.2 KB
    __shared__ _Float16 Xs[64*WS_STR];    // 9.2 KB

    f32x4 acc[4] = {};
    const int cq  = tid >> 6;
    const int lst = tid & 63;

    for (int ch = 0; ch < 4; ++ch) {
        const int c0 = ch*64;
        #pragma unroll
        for (int i = 0; i < 4; ++i) {
            int o  = i*16 + (tid>>4);
            int c4 = tid & 15;
            uint2 v = *reinterpret_cast<const uint2*>(wbp + (size_t)(o_t0 + o)*128 + (c0>>1) + c4*2);
            *reinterpret_cast<uint2*>(&Ws[o*WS_STR + c4*4]) = v;
        }
        #pragma unroll
        for (int i = 0; i < 2; ++i) {
            int c8 = i*4 + cq;                  // 8-ch group within chunk, 0..7
            uint4 v = qt[((size_t)b*32 + (c0>>3) + c8)*L_ + l0 + lst];
            *reinterpret_cast<uint4*>(&Xs[lst*WS_STR + c8*8]) = v;
        }
        __syncthreads();
        #pragma unroll
        for (int kk = 0; kk < 2; ++kk) {
            f16x8 af, bfr[4];
            af = *reinterpret_cast<const f16x8*>(&Ws[(wave*16 + orow)*WS_STR + kk*32 + kgrp*8]);
            #pragma unroll
            for (int fn = 0; fn < 4; ++fn)
                bfr[fn] = *reinterpret_cast<const f16x8*>(&Xs[(fn*16 + orow)*WS_STR + kk*32 + kgrp*8]);
            #pragma unroll
            for (int fn = 0; fn < 4; ++fn)
                acc[fn] = __builtin_amdgcn_mfma_f32_16x16x32_f16(af, bfr[fn], acc[fn], 0, 0, 0);
        }
        __syncthreads();
    }

    {
        const int o_base = o_t0 + wave*16 + kgrp*4;
        #pragma unroll
        for (int fn = 0; fn < 4; ++fn) {
            const int xl = fn*16 + orow;
            #pragma unroll
            for (int r = 0; r < 4; ++r)
                out[(size_t)(b*C_ + o_base + r)*L_ + l0 + xl] = acc[fn][r] + bo[o_base + r];
        }
    }
}

extern "C" void kernel_launch(void* const* d_in, const int* in_sizes, int n_in,
                              void* d_out, int out_size, void* d_ws, size_t ws_size,
                              hipStream_t stream) {
    const float* queries = (const float*)d_in[0];
    const float* keys    = (const float*)d_in[1];
    const float* values  = (const float*)d_in[2];
    const float* wq = (const float*)d_in[3];
    const float* bq = (const float*)d_in[4];
    const float* wk = (const float*)d_in[5];
    const float* bk = (const float*)d_in[6];
    const float* wv = (const float*)d_in[7];
    const float* bv = (const float*)d_in[8];
    const float* wo = (const float*)d_in[9];
    const float* bo = (const float*)d_in[10];
    float* out = (float*)d_out;

    uint4* qt = (uint4*)d_ws;                              // Q f16 pair-plane, attn out in-place
    uint4* kt = qt + (size_t)B_*HEADS_*NPP_*L_;            // padded pair-plane K
    uint4* vt = kt + PADT4_;                               // padded pair-plane V
    unsigned* wb = (unsigned*)(vt + PADT4_);               // f16 packed weights

    prep<<<512, 256, 0, stream>>>(wq, wk, wv, wo, wb);
    qkv_mfma<<<dim3(64, 2, 7), 256, 0, stream>>>(queries, keys, values, wb, bq, bk, bv,
                                                 (uint2*)qt, (uint2*)kt, (uint2*)vt, kt, vt);
    local_attn<<<1024, 256, 0, stream>>>(qt, kt, vt);
    out_mfma<<<dim3(64, 4, 2), 256, 0, stream>>>(qt, wb, bo, out);
}

// Round 17
// 51.310 us; speedup vs baseline: 1.0782x; 1.0290x over previous
//
#include <hip/hip_runtime.h>
#include <hip/hip_fp16.h>
#include <math.h>

#define B_ 2
#define C_ 256
#define H_ 64
#define W_ 64
#define L_ 4096
#define HEADS_ 8
#define DH_ 32
#define K_ 7
#define PAD_ 3
#define K2_ 49
#define PW_ 70
#define PPIX_ 4900
#define NPP_ 4                                  // pair-planes (8ch) per (b,h)
#define PADT4_ ((size_t)B_*HEADS_*NPP_*PPIX_)   // 313600 uint4 per padded tensor
#define WS_STR 72                               // LDS row stride in f16 elems (144B)
#define KVW_ (NPP_*K_*PW_)                      // 1960 uint4 staged window

typedef _Float16 f16x8 __attribute__((ext_vector_type(8)));
typedef _Float16 h2    __attribute__((ext_vector_type(2)));
typedef float    f32x4 __attribute__((ext_vector_type(4)));

__device__ inline h2 u2h(unsigned u) { union { unsigned u; h2 h; } c; c.u = u; return c.h; }
__device__ inline h2 cvt2h(float a, float b) {
    auto r = __builtin_amdgcn_cvt_pkrtz(a, b);      // __fp16 ext_vector(2)
    union { decltype(r) s; h2 d; } c; c.s = r; return c.d;
}
__device__ inline unsigned pkh(float a, float b) {
    union { h2 h; unsigned u; } c; c.h = cvt2h(a, b); return c.u;
}

// ---------------- Kernel A: weight pack (f16) ------------------------------
__global__ __launch_bounds__(256) void prep(
    const float* __restrict__ wq, const float* __restrict__ wk,
    const float* __restrict__ wv, const float* __restrict__ wo,
    unsigned* __restrict__ wb)
{
    int idx = blockIdx.x*256 + threadIdx.x;   // 0..131071
    const float* src = (idx < 32768) ? wq : (idx < 65536) ? wk : (idx < 98304) ? wv : wo;
    int off = (idx & 32767) * 2;
    wb[idx] = pkh(src[off], src[off+1]);
}

// ---------------- Kernel B: QKV projection via f16 MFMA + halo-zero slice ---
__global__ __launch_bounds__(256) void qkv_mfma(
    const float* __restrict__ q_in, const float* __restrict__ k_in, const float* __restrict__ v_in,
    const unsigned* __restrict__ wb,
    const float* __restrict__ bq, const float* __restrict__ bk, const float* __restrict__ bv,
    uint2* __restrict__ qt_u2, uint2* __restrict__ kt_u2, uint2* __restrict__ vt_u2,
    uint4* __restrict__ kt_u4, uint4* __restrict__ vt_u4)
{
    const int z = blockIdx.z;
    const int tid = threadIdx.x;

    if (z == 6) {
        // zero halo cells of 64 pair-planes: top3/bottom3 rows (420) + 64x6 (384)
        const int flat = blockIdx.x + 64*blockIdx.y;   // 0..127
        const uint4 zz = make_uint4(0u,0u,0u,0u);
        for (int e = flat*256 + tid; e < 64*804; e += 128*256) {
            int pl = e / 804;
            int c  = e - pl*804;
            int py, px;
            if (c < 210)      { py = c/70;            px = c%70; }
            else if (c < 420) { int c2 = c-210; py = 67 + c2/70; px = c2%70; }
            else              { int c2 = c-420; py = 3 + c2/6; int j = c2%6; px = (j<3) ? j : 64+j; }
            size_t idx = (size_t)pl*PPIX_ + (size_t)py*PW_ + px;
            kt_u4[idx] = zz;
            vt_u4[idx] = zz;
        }
        return;
    }

    const int which = z >> 1;      // 0=q,1=k,2=v
    const int b = z & 1;
    const float* X = (which==0) ? q_in : (which==1 ? k_in : v_in);
    const unsigned* wbp = wb + which*32768;
    const float* bias = (which==0) ? bq : (which==1 ? bk : bv);

    const int y    = blockIdx.x;
    const int l0   = y * 64;
    const int o_t0 = blockIdx.y * 128;
    const int lane = tid & 63, wave = tid >> 6;
    const int orow = lane & 15, kgrp = lane >> 4;

    __shared__ _Float16 Ws[128*WS_STR];   // weights [o][c-chunk]  (18.4 KB)
    __shared__ _Float16 Xs[64*WS_STR];    // input^T [l][c-chunk]  (9.2 KB)

    f32x4 acc[2][4] = {};

    for (int ch = 0; ch < 4; ++ch) {
        const int c0 = ch*64;
        #pragma unroll
        for (int i = 0; i < 8; ++i) {
            int o  = i*16 + (tid>>4);
            int c4 = tid & 15;
            uint2 v = *reinterpret_cast<const uint2*>(wbp + (size_t)(o_t0 + o)*128 + (c0>>1) + c4*2);
            *reinterpret_cast<uint2*>(&Ws[o*WS_STR + c4*4]) = v;
        }
        // Xs staging: float4 along l (4 VMEM instrs/chunk), f16 transpose writes
        #pragma unroll
        for (int i = 0; i < 4; ++i) {
            int c_loc = (tid>>4) + i*16;        // 0..63
            int l4    = (tid&15)*4;             // 0,4,...,60
            float4 xv = *reinterpret_cast<const float4*>(&X[(size_t)(b*C_ + c0 + c_loc)*L_ + l0 + l4]);
            Xs[(l4+0)*WS_STR + c_loc] = (_Float16)xv.x;
            Xs[(l4+1)*WS_STR + c_loc] = (_Float16)xv.y;
            Xs[(l4+2)*WS_STR + c_loc] = (_Float16)xv.z;
            Xs[(l4+3)*WS_STR + c_loc] = (_Float16)xv.w;
        }
        __syncthreads();
        #pragma unroll
        for (int kk = 0; kk < 2; ++kk) {
            f16x8 af[2], bfr[4];
            #pragma unroll
            for (int fo = 0; fo < 2; ++fo)
                af[fo] = *reinterpret_cast<const f16x8*>(&Ws[(wave*32 + fo*16 + orow)*WS_STR + kk*32 + kgrp*8]);
            #pragma unroll
            for (int fn = 0; fn < 4; ++fn)
                bfr[fn] = *reinterpret_cast<const f16x8*>(&Xs[(fn*16 + orow)*WS_STR + kk*32 + kgrp*8]);
            #pragma unroll
            for (int fo = 0; fo < 2; ++fo)
                #pragma unroll
                for (int fn = 0; fn < 4; ++fn)
                    acc[fo][fn] = __builtin_amdgcn_mfma_f32_16x16x32_f16(af[fo], bfr[fn], acc[fo][fn], 0, 0, 0);
        }
        __syncthreads();
    }

    #pragma unroll
    for (int fo = 0; fo < 2; ++fo) {
        const int og = o_t0 + wave*32 + fo*16 + kgrp*4;
        const float4 b4 = *reinterpret_cast<const float4*>(&bias[og]);
        const size_t pp = (size_t)(b*32 + (og >> 3));   // pair-plane index
        const int half = (og >> 2) & 1;
        #pragma unroll
        for (int fn = 0; fn < 4; ++fn) {
            const int xl = fn*16 + orow;
            uint2 r = make_uint2(pkh(acc[fo][fn][0] + b4.x, acc[fo][fn][1] + b4.y),
                                 pkh(acc[fo][fn][2] + b4.z, acc[fo][fn][3] + b4.w));
            if (which == 0) {
                qt_u2[(pp*L_ + l0 + xl)*2 + half] = r;
            } else {
                uint2* dst = (which==1) ? kt_u2 : vt_u2;
                dst[(pp*PPIX_ + (size_t)(y+PAD_)*PW_ + (xl+PAD_))*2 + half] = r;
            }
        }
    }
}

// ---------------- Kernel C: 7x7 local attention, LDS-staged K/V window ------
// Block = (plane=b*8+h, image row y), 256 threads (4 waves), grid 1024.
// K window (4pp x 7rows x 70) staged as pure uint4 copies -> each byte crosses
// L1 once; taps become ds_read_b128 (2-lane/bank aliasing = free). V staged
// over the same buffer; its latency hides under the softmax sum.
__global__ __launch_bounds__(256) void local_attn(
    uint4* __restrict__ qt, const uint4* __restrict__ kt, const uint4* __restrict__ vt)
{
    const int tid = threadIdx.x;
    const int w = tid >> 6, x = tid & 63;
    const int bid = blockIdx.x;
    const int plane = bid & 15;      // plane -> XCD plane%8: K/V L2-resident per XCD
    const int y = bid >> 4;          // 0..63

    const uint4* kb = kt + (size_t)plane*NPP_*PPIX_;
    const uint4* vb = vt + (size_t)plane*NPP_*PPIX_;
    uint4* qpl = qt + (size_t)plane*NPP_*L_;

    __shared__ uint4 KV[KVW_];       // [pp][r 0..6][xp 0..69]: 31.36 KB
    __shared__ float S[K2_][64];     // P = exp(logit*scale): 12.25 KB  (43.9 KB total)

    const float scale = 0.0625f; // 1/sqrt(256)

    // ---- Q loads first (latency overlaps K staging) ----
    uint4 qu[NPP_];
    #pragma unroll
    for (int pp=0; pp<NPP_; ++pp) qu[pp] = qpl[(size_t)pp*L_ + y*W_ + x];

    // ---- stage K window: pure uint4 copy, fully coalesced ----
    #pragma unroll
    for (int i = 0; i < 8; ++i) {
        int e = tid + i*256;
        if (e < KVW_) {
            int pp = e / (K_*PW_);
            int rem = e - pp*(K_*PW_);
            int r = rem / PW_, xp = rem - r*PW_;
            KV[e] = kb[(size_t)pp*PPIX_ + (size_t)(y + r)*PW_ + xp];
        }
    }
    __syncthreads();

    // ---- QK: my window rows r = w and w+4, from LDS ----
    float lg[2][K_] = {};
    #pragma unroll
    for (int pp=0; pp<NPP_; ++pp) {
        const h2 q0 = u2h(qu[pp].x), q1 = u2h(qu[pp].y), q2 = u2h(qu[pp].z), q3 = u2h(qu[pp].w);
        #pragma unroll
        for (int rr=0; rr<2; ++rr) {
            const int r = w + rr*4;
            if (r > 6) continue;                  // only w=3,rr=1 skips (uniform)
            const uint4* row = &KV[(pp*K_ + r)*PW_ + x];
            #pragma unroll
            for (int kx=0; kx<K_; ++kx) {
                uint4 kk = row[kx];
                float d = lg[rr][kx];
                d = __builtin_amdgcn_fdot2(q0, u2h(kk.x), d, false);
                d = __builtin_amdgcn_fdot2(q1, u2h(kk.y), d, false);
                d = __builtin_amdgcn_fdot2(q2, u2h(kk.z), d, false);
                d = __builtin_amdgcn_fdot2(q3, u2h(kk.w), d, false);
                lg[rr][kx] = d;
            }
        }
    }
    #pragma unroll
    for (int rr=0; rr<2; ++rr) {
        const int r = w + rr*4;
        if (r <= 6) {
            #pragma unroll
            for (int kx=0; kx<K_; ++kx) S[r*K_+kx][x] = __expf(lg[rr][kx]*scale);
        }
    }
    __syncthreads();   // S complete AND all K reads of KV done

    // ---- stage V over the same buffer (loads in flight during sum below) ----
    #pragma unroll
    for (int i = 0; i < 8; ++i) {
        int e = tid + i*256;
        if (e < KVW_) {
            int pp = e / (K_*PW_);
            int rem = e - pp*(K_*PW_);
            int r = rem / PW_, xp = rem - r*PW_;
            KV[e] = vb[(size_t)pp*PPIX_ + (size_t)(y + r)*PW_ + xp];
        }
    }

    // ---- denominator: plain sum of P from LDS (overlaps V staging latency) ----
    float sum = 0.f;
    #pragma unroll
    for (int i=0;i<K2_;++i) sum += S[i][x];
    const float inv = 1.0f/sum;
    __syncthreads();   // V staged

    // ---- PV: my pair-plane (= w, 8 channels), V from LDS ----
    float4 a0 = make_float4(0.f,0.f,0.f,0.f);
    float4 a1 = make_float4(0.f,0.f,0.f,0.f);
    #pragma unroll
    for (int r=0; r<K_; ++r) {
        const uint4* row = &KV[(w*K_ + r)*PW_ + x];
        h2 ra0 = (h2)0, ra1 = (h2)0, rb0 = (h2)0, rb1 = (h2)0;
        #pragma unroll
        for (int kx=0; kx<K_; ++kx) {
            const float p = S[r*K_+kx][x];
            const h2 p2 = cvt2h(p, p);
            uint4 u = row[kx];
            ra0 += p2 * u2h(u.x);
            ra1 += p2 * u2h(u.y);
            rb0 += p2 * u2h(u.z);
            rb1 += p2 * u2h(u.w);
        }
        a0.x += (float)ra0[0]; a0.y += (float)ra0[1];
        a0.z += (float)ra1[0]; a0.w += (float)ra1[1];
        a1.x += (float)rb0[0]; a1.y += (float)rb0[1];
        a1.z += (float)rb1[0]; a1.w += (float)rb1[1];
    }
    qpl[(size_t)w*L_ + y*W_ + x] = make_uint4(pkh(a0.x*inv, a0.y*inv), pkh(a0.z*inv, a0.w*inv),
                                              pkh(a1.x*inv, a1.y*inv), pkh(a1.z*inv, a1.w*inv));
}

// ---------------- Kernel D: output projection via f16 MFMA (64-o tiles) -----
__global__ __launch_bounds__(256) void out_mfma(
    const uint4* __restrict__ qt, const unsigned* __restrict__ wb,
    const float* __restrict__ bo, float* __restrict__ out)
{
    const int b    = blockIdx.z;
    const int l0   = blockIdx.x * 64;
    const int o_t0 = blockIdx.y * 64;
    const unsigned* wbp = wb + 3*32768;
    const int tid  = threadIdx.x;
    const int lane = tid & 63, wave = tid >> 6;
    const int orow = lane & 15, kgrp = lane >> 4;

    __shared__ _Float16 Ws[64*WS_STR];    // 9.2 KB
    __shared__ _Float16 Xs[64*WS_STR];    // 9.2 KB

    f32x4 acc[4] = {};
    const int cq  = tid >> 6;
    const int lst = tid & 63;

    for (int ch = 0; ch < 4; ++ch) {
        const int c0 = ch*64;
        #pragma unroll
        for (int i = 0; i < 4; ++i) {
            int o  = i*16 + (tid>>4);
            int c4 = tid & 15;
            uint2 v = *reinterpret_cast<const uint2*>(wbp + (size_t)(o_t0 + o)*128 + (c0>>1) + c4*2);
            *reinterpret_cast<uint2*>(&Ws[o*WS_STR + c4*4]) = v;
        }
        #pragma unroll
        for (int i = 0; i < 2; ++i) {
            int c8 = i*4 + cq;                  // 8-ch group within chunk, 0..7
            uint4 v = qt[((size_t)b*32 + (c0>>3) + c8)*L_ + l0 + lst];
            *reinterpret_cast<uint4*>(&Xs[lst*WS_STR + c8*8]) = v;
        }
        __syncthreads();
        #pragma unroll
        for (int kk = 0; kk < 2; ++kk) {
            f16x8 af, bfr[4];
            af = *reinterpret_cast<const f16x8*>(&Ws[(wave*16 + orow)*WS_STR + kk*32 + kgrp*8]);
            #pragma unroll
            for (int fn = 0; fn < 4; ++fn)
                bfr[fn] = *reinterpret_cast<const f16x8*>(&Xs[(fn*16 + orow)*WS_STR + kk*32 + kgrp*8]);
            #pragma unroll
            for (int fn = 0; fn < 4; ++fn)
                acc[fn] = __builtin_amdgcn_mfma_f32_16x16x32_f16(af, bfr[fn], acc[fn], 0, 0, 0);
        }
        __syncthreads();
    }

    {
        const int o_base = o_t0 + wave*16 + kgrp*4;
        #pragma unroll
        for (int fn = 0; fn < 4; ++fn) {
            const int xl = fn*16 + orow;
            #pragma unroll
            for (int r = 0; r < 4; ++r)
                out[(size_t)(b*C_ + o_base + r)*L_ + l0 + xl] = acc[fn][r] + bo[o_base + r];
        }
    }
}

extern "C" void kernel_launch(void* const* d_in, const int* in_sizes, int n_in,
                              void* d_out, int out_size, void* d_ws, size_t ws_size,
                              hipStream_t stream) {
    const float* queries = (const float*)d_in[0];
    const float* keys    = (const float*)d_in[1];
    const float* values  = (const float*)d_in[2];
    const float* wq = (const float*)d_in[3];
    const float* bq = (const float*)d_in[4];
    const float* wk = (const float*)d_in[5];
    const float* bk = (const float*)d_in[6];
    const float* wv = (const float*)d_in[7];
    const float* bv = (const float*)d_in[8];
    const float* wo = (const float*)d_in[9];
    const float* bo = (const float*)d_in[10];
    float* out = (float*)d_out;

    uint4* qt = (uint4*)d_ws;                              // Q f16 pair-plane, attn out in-place
    uint4* kt = qt + (size_t)B_*HEADS_*NPP_*L_;            // padded pair-plane K
    uint4* vt = kt + PADT4_;                               // padded pair-plane V
    unsigned* wb = (unsigned*)(vt + PADT4_);               // f16 packed weights

    prep<<<512, 256, 0, stream>>>(wq, wk, wv, wo, wb);
    qkv_mfma<<<dim3(64, 2, 7), 256, 0, stream>>>(queries, keys, values, wb, bq, bk, bv,
                                                 (uint2*)qt, (uint2*)kt, (uint2*)vt, kt, vt);
    local_attn<<<1024, 256, 0, stream>>>(qt, kt, vt);
    out_mfma<<<dim3(64, 4, 2), 256, 0, stream>>>(qt, wb, bo, out);
}

// Round 18
// 46.350 us; speedup vs baseline: 1.1936x; 1.1070x over previous
//
#include <hip/hip_runtime.h>
#include <hip/hip_fp16.h>
#include <math.h>

#define B_ 2
#define C_ 256
#define H_ 64
#define W_ 64
#define L_ 4096
#define HEADS_ 8
#define DH_ 32
#define K_ 7
#define PAD_ 3
#define K2_ 49
#define PW_ 70
#define PPIX_ 4900
#define NPP_ 4                                  // pair-planes (8ch) per (b,h)
#define PADT4_ ((size_t)B_*HEADS_*NPP_*PPIX_)   // 313600 uint4 per padded tensor
#define WS_STR 72                               // LDS row stride in f16 elems (144B = 9x16B)
#define KVW_ (NPP_*K_*PW_)                      // 1960 uint4 staged window

typedef _Float16 f16x8 __attribute__((ext_vector_type(8)));
typedef _Float16 h2    __attribute__((ext_vector_type(2)));
typedef float    f32x4 __attribute__((ext_vector_type(4)));

__device__ inline h2 u2h(unsigned u) { union { unsigned u; h2 h; } c; c.u = u; return c.h; }
__device__ inline h2 cvt2h(float a, float b) {
    auto r = __builtin_amdgcn_cvt_pkrtz(a, b);      // __fp16 ext_vector(2)
    union { decltype(r) s; h2 d; } c; c.s = r; return c.d;
}
__device__ inline unsigned pkh(float a, float b) {
    union { h2 h; unsigned u; } c; c.h = cvt2h(a, b); return c.u;
}

// ---------------- Kernel A: weight pack (f16) ------------------------------
__global__ __launch_bounds__(256) void prep(
    const float* __restrict__ wq, const float* __restrict__ wk,
    const float* __restrict__ wv, const float* __restrict__ wo,
    unsigned* __restrict__ wb)
{
    int idx = blockIdx.x*256 + threadIdx.x;   // 0..131071
    const float* src = (idx < 32768) ? wq : (idx < 65536) ? wk : (idx < 98304) ? wv : wo;
    int off = (idx & 32767) * 2;
    wb[idx] = pkh(src[off], src[off+1]);
}

// ---------------- Kernel B: QKV projection via f16 MFMA + halo-zero slice ---
// z = 0..5: GEMM (which = z>>1, b = z&1), 128 o x 64 l per block.
// z = 6:    K/V halo zeroing (uint4 pair-plane layout, direct enumeration).
__global__ __launch_bounds__(256) void qkv_mfma(
    const float* __restrict__ q_in, const float* __restrict__ k_in, const float* __restrict__ v_in,
    const unsigned* __restrict__ wb,
    const float* __restrict__ bq, const float* __restrict__ bk, const float* __restrict__ bv,
    uint2* __restrict__ qt_u2, uint2* __restrict__ kt_u2, uint2* __restrict__ vt_u2,
    uint4* __restrict__ kt_u4, uint4* __restrict__ vt_u4)
{
    const int z = blockIdx.z;
    const int tid = threadIdx.x;

    if (z == 6) {
        // zero halo cells of 64 pair-planes: top3/bottom3 rows (420) + 64x6 (384)
        const int flat = blockIdx.x + 64*blockIdx.y;   // 0..127
        const uint4 zz = make_uint4(0u,0u,0u,0u);
        for (int e = flat*256 + tid; e < 64*804; e += 128*256) {
            int pl = e / 804;
            int c  = e - pl*804;
            int py, px;
            if (c < 210)      { py = c/70;            px = c%70; }
            else if (c < 420) { int c2 = c-210; py = 67 + c2/70; px = c2%70; }
            else              { int c2 = c-420; py = 3 + c2/6; int j = c2%6; px = (j<3) ? j : 64+j; }
            size_t idx = (size_t)pl*PPIX_ + (size_t)py*PW_ + px;
            kt_u4[idx] = zz;
            vt_u4[idx] = zz;
        }
        return;
    }

    const int which = z >> 1;      // 0=q,1=k,2=v
    const int b = z & 1;
    const float* X = (which==0) ? q_in : (which==1 ? k_in : v_in);
    const unsigned* wbp = wb + which*32768;
    const float* bias = (which==0) ? bq : (which==1 ? bk : bv);

    const int y    = blockIdx.x;
    const int l0   = y * 64;
    const int o_t0 = blockIdx.y * 128;
    const int lane = tid & 63, wave = tid >> 6;
    const int orow = lane & 15, kgrp = lane >> 4;

    __shared__ _Float16 Ws[128*WS_STR];   // weights [o][c-chunk]  (18.4 KB)
    __shared__ _Float16 Xs[64*WS_STR];    // input^T [l][c-chunk]  (9.2 KB)

    f32x4 acc[2][4] = {};

    for (int ch = 0; ch < 4; ++ch) {
        const int c0 = ch*64;
        // Ws staging: uint4 (4 loads + 4 16B ds-writes per thread per chunk)
        #pragma unroll
        for (int i = 0; i < 4; ++i) {
            int flat = i*256 + tid;             // 0..1023
            int o    = flat >> 3;               // 0..127
            int c16  = flat & 7;                // uint4 index within 64-c chunk
            uint4 v = *reinterpret_cast<const uint4*>(wbp + (size_t)(o_t0 + o)*128 + ch*32 + c16*4);
            *reinterpret_cast<uint4*>(&Ws[o*WS_STR + c16*8]) = v;
        }
        // Xs staging: paired-c float4 loads, packed u32 transpose writes
        #pragma unroll
        for (int i = 0; i < 2; ++i) {
            int c_loc = (tid>>4)*2 + i*32;      // even c: 0,2,..,62
            int l4    = (tid&15)*4;             // 0,4,...,60
            float4 x0 = *reinterpret_cast<const float4*>(&X[(size_t)(b*C_ + c0 + c_loc    )*L_ + l0 + l4]);
            float4 x1 = *reinterpret_cast<const float4*>(&X[(size_t)(b*C_ + c0 + c_loc + 1)*L_ + l0 + l4]);
            *reinterpret_cast<unsigned*>(&Xs[(l4+0)*WS_STR + c_loc]) = pkh(x0.x, x1.x);
            *reinterpret_cast<unsigned*>(&Xs[(l4+1)*WS_STR + c_loc]) = pkh(x0.y, x1.y);
            *reinterpret_cast<unsigned*>(&Xs[(l4+2)*WS_STR + c_loc]) = pkh(x0.z, x1.z);
            *reinterpret_cast<unsigned*>(&Xs[(l4+3)*WS_STR + c_loc]) = pkh(x0.w, x1.w);
        }
        __syncthreads();
        #pragma unroll
        for (int kk = 0; kk < 2; ++kk) {
            f16x8 af[2], bfr[4];
            #pragma unroll
            for (int fo = 0; fo < 2; ++fo)
                af[fo] = *reinterpret_cast<const f16x8*>(&Ws[(wave*32 + fo*16 + orow)*WS_STR + kk*32 + kgrp*8]);
            #pragma unroll
            for (int fn = 0; fn < 4; ++fn)
                bfr[fn] = *reinterpret_cast<const f16x8*>(&Xs[(fn*16 + orow)*WS_STR + kk*32 + kgrp*8]);
            #pragma unroll
            for (int fo = 0; fo < 2; ++fo)
                #pragma unroll
                for (int fn = 0; fn < 4; ++fn)
                    acc[fo][fn] = __builtin_amdgcn_mfma_f32_16x16x32_f16(af[fo], bfr[fn], acc[fo][fn], 0, 0, 0);
        }
        __syncthreads();
    }

    #pragma unroll
    for (int fo = 0; fo < 2; ++fo) {
        const int og = o_t0 + wave*32 + fo*16 + kgrp*4;
        const float4 b4 = *reinterpret_cast<const float4*>(&bias[og]);
        const size_t pp = (size_t)(b*32 + (og >> 3));   // pair-plane index
        const int half = (og >> 2) & 1;
        #pragma unroll
        for (int fn = 0; fn < 4; ++fn) {
            const int xl = fn*16 + orow;
            uint2 r = make_uint2(pkh(acc[fo][fn][0] + b4.x, acc[fo][fn][1] + b4.y),
                                 pkh(acc[fo][fn][2] + b4.z, acc[fo][fn][3] + b4.w));
            if (which == 0) {
                qt_u2[(pp*L_ + l0 + xl)*2 + half] = r;
            } else {
                uint2* dst = (which==1) ? kt_u2 : vt_u2;
                dst[(pp*PPIX_ + (size_t)(y+PAD_)*PW_ + (xl+PAD_))*2 + half] = r;
            }
        }
    }
}

// ---------------- Kernel C: 7x7 local attention, LDS-staged K/V window ------
// Block = (plane=b*8+h, image row y), 256 threads (4 waves), grid 1024.
__global__ __launch_bounds__(256) void local_attn(
    uint4* __restrict__ qt, const uint4* __restrict__ kt, const uint4* __restrict__ vt)
{
    const int tid = threadIdx.x;
    const int w = tid >> 6, x = tid & 63;
    const int bid = blockIdx.x;
    const int plane = bid & 15;      // plane -> XCD plane%8: K/V L2-resident per XCD
    const int y = bid >> 4;          // 0..63

    const uint4* kb = kt + (size_t)plane*NPP_*PPIX_;
    const uint4* vb = vt + (size_t)plane*NPP_*PPIX_;
    uint4* qpl = qt + (size_t)plane*NPP_*L_;

    __shared__ uint4 KV[KVW_];       // [pp][r 0..6][xp 0..69]: 31.36 KB
    __shared__ float S[K2_][64];     // P = exp(logit*scale): 12.25 KB  (43.9 KB total)

    const float scale = 0.0625f; // 1/sqrt(256)

    // ---- Q loads first (latency overlaps K staging) ----
    uint4 qu[NPP_];
    #pragma unroll
    for (int pp=0; pp<NPP_; ++pp) qu[pp] = qpl[(size_t)pp*L_ + y*W_ + x];

    // ---- stage K window: pure uint4 copy, fully coalesced ----
    #pragma unroll
    for (int i = 0; i < 8; ++i) {
        int e = tid + i*256;
        if (e < KVW_) {
            int pp = e / (K_*PW_);
            int rem = e - pp*(K_*PW_);
            int r = rem / PW_, xp = rem - r*PW_;
            KV[e] = kb[(size_t)pp*PPIX_ + (size_t)(y + r)*PW_ + xp];
        }
    }
    __syncthreads();

    // ---- QK: my window rows r = w and w+4, from LDS ----
    float lg[2][K_] = {};
    #pragma unroll
    for (int pp=0; pp<NPP_; ++pp) {
        const h2 q0 = u2h(qu[pp].x), q1 = u2h(qu[pp].y), q2 = u2h(qu[pp].z), q3 = u2h(qu[pp].w);
        #pragma unroll
        for (int rr=0; rr<2; ++rr) {
            const int r = w + rr*4;
            if (r > 6) continue;                  // only w=3,rr=1 skips (uniform)
            const uint4* row = &KV[(pp*K_ + r)*PW_ + x];
            #pragma unroll
            for (int kx=0; kx<K_; ++kx) {
                uint4 kk = row[kx];
                float d = lg[rr][kx];
                d = __builtin_amdgcn_fdot2(q0, u2h(kk.x), d, false);
                d = __builtin_amdgcn_fdot2(q1, u2h(kk.y), d, false);
                d = __builtin_amdgcn_fdot2(q2, u2h(kk.z), d, false);
                d = __builtin_amdgcn_fdot2(q3, u2h(kk.w), d, false);
                lg[rr][kx] = d;
            }
        }
    }
    #pragma unroll
    for (int rr=0; rr<2; ++rr) {
        const int r = w + rr*4;
        if (r <= 6) {
            #pragma unroll
            for (int kx=0; kx<K_; ++kx) S[r*K_+kx][x] = __expf(lg[rr][kx]*scale);
        }
    }
    __syncthreads();   // S complete AND all K reads of KV done

    // ---- stage V over the same buffer (loads in flight during sum below) ----
    #pragma unroll
    for (int i = 0; i < 8; ++i) {
        int e = tid + i*256;
        if (e < KVW_) {
            int pp = e / (K_*PW_);
            int rem = e - pp*(K_*PW_);
            int r = rem / PW_, xp = rem - r*PW_;
            KV[e] = vb[(size_t)pp*PPIX_ + (size_t)(y + r)*PW_ + xp];
        }
    }

    // ---- denominator: plain sum of P from LDS (overlaps V staging latency) ----
    float sum = 0.f;
    #pragma unroll
    for (int i=0;i<K2_;++i) sum += S[i][x];
    const float inv = 1.0f/sum;
    __syncthreads();   // V staged

    // ---- PV: my pair-plane (= w, 8 channels), V from LDS ----
    float4 a0 = make_float4(0.f,0.f,0.f,0.f);
    float4 a1 = make_float4(0.f,0.f,0.f,0.f);
    #pragma unroll
    for (int r=0; r<K_; ++r) {
        const uint4* row = &KV[(w*K_ + r)*PW_ + x];
        h2 ra0 = (h2)0, ra1 = (h2)0, rb0 = (h2)0, rb1 = (h2)0;
        #pragma unroll
        for (int kx=0; kx<K_; ++kx) {
            const float p = S[r*K_+kx][x];
            const h2 p2 = cvt2h(p, p);
            uint4 u = row[kx];
            ra0 += p2 * u2h(u.x);
            ra1 += p2 * u2h(u.y);
            rb0 += p2 * u2h(u.z);
            rb1 += p2 * u2h(u.w);
        }
        a0.x += (float)ra0[0]; a0.y += (float)ra0[1];
        a0.z += (float)ra1[0]; a0.w += (float)ra1[1];
        a1.x += (float)rb0[0]; a1.y += (float)rb0[1];
        a1.z += (float)rb1[0]; a1.w += (float)rb1[1];
    }
    qpl[(size_t)w*L_ + y*W_ + x] = make_uint4(pkh(a0.x*inv, a0.y*inv), pkh(a0.z*inv, a0.w*inv),
                                              pkh(a1.x*inv, a1.y*inv), pkh(a1.z*inv, a1.w*inv));
}

// ---------------- Kernel D: output projection via f16 MFMA (64-o tiles) -----
__global__ __launch_bounds__(256) void out_mfma(
    const uint4* __restrict__ qt, const unsigned* __restrict__ wb,
    const float* __restrict__ bo, float* __restrict__ out)
{
    const int b    = blockIdx.z;
    const int l0   = blockIdx.x * 64;
    const int o_t0 = blockIdx.y * 64;
    const unsigned* wbp = wb + 3*32768;
    const int tid  = threadIdx.x;
    const int lane = tid & 63, wave = tid >> 6;
    const int orow = lane & 15, kgrp = lane >> 4;

    __shared__ _Float16 Ws[64*WS_STR];    // 9.2 KB
    __shared__ _Float16 Xs[64*WS_STR];    // 9.2 KB

    f32x4 acc[4] = {};
    const int cq  = tid >> 6;
    const int lst = tid & 63;

    for (int ch = 0; ch < 4; ++ch) {
        const int c0 = ch*64;
        // Ws staging: uint4 (2 loads + 2 16B ds-writes per thread per chunk)
        #pragma unroll
        for (int i = 0; i < 2; ++i) {
            int flat = i*256 + tid;             // 0..511
            int o    = flat >> 3;               // 0..63
            int c16  = flat & 7;
            uint4 v = *reinterpret_cast<const uint4*>(wbp + (size_t)(o_t0 + o)*128 + ch*32 + c16*4);
            *reinterpret_cast<uint4*>(&Ws[o*WS_STR + c16*8]) = v;
        }
        #pragma unroll
        for (int i = 0; i < 2; ++i) {
            int c8 = i*4 + cq;                  // 8-ch group within chunk, 0..7
            uint4 v = qt[((size_t)b*32 + (c0>>3) + c8)*L_ + l0 + lst];
            *reinterpret_cast<uint4*>(&Xs[lst*WS_STR + c8*8]) = v;
        }
        __syncthreads();
        #pragma unroll
        for (int kk = 0; kk < 2; ++kk) {
            f16x8 af, bfr[4];
            af = *reinterpret_cast<const f16x8*>(&Ws[(wave*16 + orow)*WS_STR + kk*32 + kgrp*8]);
            #pragma unroll
            for (int fn = 0; fn < 4; ++fn)
                bfr[fn] = *reinterpret_cast<const f16x8*>(&Xs[(fn*16 + orow)*WS_STR + kk*32 + kgrp*8]);
            #pragma unroll
            for (int fn = 0; fn < 4; ++fn)
                acc[fn] = __builtin_amdgcn_mfma_f32_16x16x32_f16(af, bfr[fn], acc[fn], 0, 0, 0);
        }
        __syncthreads();
    }

    {
        const int o_base = o_t0 + wave*16 + kgrp*4;
        #pragma unroll
        for (int fn = 0; fn < 4; ++fn) {
            const int xl = fn*16 + orow;
            #pragma unroll
            for (int r = 0; r < 4; ++r)
                out[(size_t)(b*C_ + o_base + r)*L_ + l0 + xl] = acc[fn][r] + bo[o_base + r];
        }
    }
}

extern "C" void kernel_launch(void* const* d_in, const int* in_sizes, int n_in,
                              void* d_out, int out_size, void* d_ws, size_t ws_size,
                              hipStream_t stream) {
    const float* queries = (const float*)d_in[0];
    const float* keys    = (const float*)d_in[1];
    const float* values  = (const float*)d_in[2];
    const float* wq = (const float*)d_in[3];
    const float* bq = (const float*)d_in[4];
    const float* wk = (const float*)d_in[5];
    const float* bk = (const float*)d_in[6];
    const float* wv = (const float*)d_in[7];
    const float* bv = (const float*)d_in[8];
    const float* wo = (const float*)d_in[9];
    const float* bo = (const float*)d_in[10];
    float* out = (float*)d_out;

    uint4* qt = (uint4*)d_ws;                              // Q f16 pair-plane, attn out in-place
    uint4* kt = qt + (size_t)B_*HEADS_*NPP_*L_;            // padded pair-plane K
    uint4* vt = kt + PADT4_;                               // padded pair-plane V
    unsigned* wb = (unsigned*)(vt + PADT4_);               // f16 packed weights

    prep<<<512, 256, 0, stream>>>(wq, wk, wv, wo, wb);
    qkv_mfma<<<dim3(64, 2, 7), 256, 0, stream>>>(queries, keys, values, wb, bq, bk, bv,
                                                 (uint2*)qt, (uint2*)kt, (uint2*)vt, kt, vt);
    local_attn<<<1024, 256, 0, stream>>>(qt, kt, vt);
    out_mfma<<<dim3(64, 4, 2), 256, 0, stream>>>(qt, wb, bo, out);
}